// Round 15
// baseline (131.258 us; speedup 1.0000x reference)
//
#include <hip/hip_runtime.h>
#include <math.h>

#define NP 8192
#define NF 16384
#define GQ 8

// ---------------------------------------------------------------------------
// K0: face centers in f64 + |c|^2 (np: c=(v0+v1+v2)/3), plus Adagrad clr table
// ---------------------------------------------------------------------------
__global__ __launch_bounds__(256) void k_centers(const float* __restrict__ mV,
                                                 const int* __restrict__ mF,
                                                 double* __restrict__ ctr,
                                                 double* __restrict__ clrtab) {
    if (blockIdx.x == 0 && threadIdx.x < 50) {
        clrtab[threadIdx.x] = 0.2 / (1.0 + (double)threadIdx.x * 0.1);
    }
    int f = blockIdx.x * 256 + threadIdx.x;
    if (f >= NF) return;
    int i0 = mF[3*f+0], i1 = mF[3*f+1], i2 = mF[3*f+2];
    double cx = ((double)mV[3*i0+0] + (double)mV[3*i1+0] + (double)mV[3*i2+0]) / 3.0;
    double cy = ((double)mV[3*i0+1] + (double)mV[3*i1+1] + (double)mV[3*i2+1]) / 3.0;
    double cz = ((double)mV[3*i0+2] + (double)mV[3*i1+2] + (double)mV[3*i2+2]) / 3.0;
    ctr[4*f+0] = cx; ctr[4*f+1] = cy; ctr[4*f+2] = cz;
    ctr[4*f+3] = cx*cx + cy*cy + cz*cz;
}

// ---------------------------------------------------------------------------
// K1: brute-force 1-NN — EXACT R11 kernel bits (measured 52µs, VGPR=60, no
// spill; every f32/split variant since lost to it). key = cc - 2 q.c;
// winner's true d2 recomputed with np's association; lex (key,idx) ==
// jnp.argmin first-index tie-break.
// ---------------------------------------------------------------------------
__global__ __launch_bounds__(256) void k_knn(const float* __restrict__ qV,
                                             const double* __restrict__ ctr,
                                             float* __restrict__ out,
                                             int* __restrict__ fidx_ws,
                                             int* __restrict__ valid_ws) {
    int pbase = blockIdx.x * GQ;
    double qx[GQ], qy[GQ], qz[GQ];
    #pragma unroll
    for (int g = 0; g < GQ; ++g) {
        int p = pbase + g;
        qx[g] = (double)qV[3*p+0];
        qy[g] = (double)qV[3*p+1];
        qz[g] = (double)qV[3*p+2];
    }
    double best[GQ]; int bidx[GQ];
    #pragma unroll
    for (int g = 0; g < GQ; ++g) { best[g] = 1e300; bidx[g] = 0x7fffffff; }

    const double4* ctr4 = (const double4*)ctr;
    #pragma unroll 2
    for (int f = threadIdx.x; f < NF; f += 256) {
        double4 c = ctr4[f];
        #pragma unroll
        for (int g = 0; g < GQ; ++g) {
            double dot = qx[g]*c.x + qy[g]*c.y + qz[g]*c.z;
            double key = c.w - 2.0*dot;
            if (key < best[g]) { best[g] = key; bidx[g] = f; }  // f ascends: < = lex
        }
    }
    // wave (64-lane) reduction, lexicographic (key, idx)
    #pragma unroll
    for (int off = 32; off > 0; off >>= 1) {
        #pragma unroll
        for (int g = 0; g < GQ; ++g) {
            double ov = __shfl_down(best[g], off);
            int    oi = __shfl_down(bidx[g], off);
            if (ov < best[g] || (ov == best[g] && oi < bidx[g])) { best[g] = ov; bidx[g] = oi; }
        }
    }
    __shared__ double sv[4][GQ];
    __shared__ int    si[4][GQ];
    int wid = threadIdx.x >> 6, lane = threadIdx.x & 63;
    if (lane == 0) {
        #pragma unroll
        for (int g = 0; g < GQ; ++g) { sv[wid][g] = best[g]; si[wid][g] = bidx[g]; }
    }
    __syncthreads();
    if (threadIdx.x == 0) {
        for (int g = 0; g < GQ; ++g) {
            double bv = sv[0][g]; int bi = si[0][g];
            for (int w2 = 1; w2 < 4; ++w2) {
                double ov = sv[w2][g]; int oi = si[w2][g];
                if (ov < bv || (ov == bv && oi < bi)) { bv = ov; bi = oi; }
            }
            int p = pbase + g;
            double4 c = ctr4[bi];
            double dot = qx[g]*c.x + qy[g]*c.y + qz[g]*c.z;
            double qq  = qx[g]*qx[g] + qy[g]*qy[g] + qz[g]*qz[g];
            double d2  = (qq - 2.0*dot) + c.w;
            int outlier = (d2 > 0.1) ? 1 : 0;
            fidx_ws[p]  = bi;
            valid_ws[p] = 1 - outlier;
            out[p]          = (float)bi;              // output 0: spt_fidx
            out[3*NP + p]   = outlier ? 1.0f : 0.0f;  // output 2: outlier_mask
        }
    }
}

// ---------------------------------------------------------------------------
// K2: denom = max(#valid, 1)
// ---------------------------------------------------------------------------
__global__ __launch_bounds__(256) void k_denom(const int* __restrict__ valid_ws,
                                               double* __restrict__ denom) {
    __shared__ int s[256];
    int acc = 0;
    for (int i = threadIdx.x; i < NP; i += 256) acc += valid_ws[i];
    s[threadIdx.x] = acc;
    __syncthreads();
    for (int off = 128; off > 0; off >>= 1) {
        if (threadIdx.x < off) s[threadIdx.x] += s[threadIdx.x + off];
        __syncthreads();
    }
    if (threadIdx.x == 0) {
        double d = (double)s[0];
        denom[0] = d > 1.0 ? d : 1.0;
    }
}

// ---------------------------------------------------------------------------
// K3: per-point 2x50-step Adagrad, TWO INDEPENDENT POINTS PER THREAD.
// k_opt is latency-bound (R13: 47.9µs @1.3% occupancy — 128 waves chip-wide,
// each f64 chain op pays full pipeline latency, ~1150cyc/iter vs ~300 issue).
// Interleaving 2 independent chains lets the scheduler fill latency slots.
// PER-POINT ARITHMETIC IS BIT-IDENTICAL to the R4-R14 passing version (same
// expressions, same order; [2]-arrays fully unrolled -> static indices ->
// registers). Invalid points compute harmlessly and write 1/3.
// ---------------------------------------------------------------------------
__global__ __launch_bounds__(64, 1) void k_opt(const float* __restrict__ qV,
                                               const float* __restrict__ qN,
                                               const float* __restrict__ mV,
                                               const int* __restrict__ mF,
                                               const float* __restrict__ mN,
                                               const int* __restrict__ fidx_ws,
                                               const int* __restrict__ valid_ws,
                                               const double* __restrict__ denomp,
                                               const double* __restrict__ clrtab,
                                               float* __restrict__ out) {
    int t = blockIdx.x * 64 + threadIdx.x;      // 4096 threads, 2 points each
    double inv_denom = 1.0 / denomp[0];
    const float third = (float)(1.0/3.0);

    int    vld[2];
    double Eux[2], Euy[2], Euz[2], Ewx[2], Ewy[2], Ewz[2];
    double Fux[2], Fuy[2], Fuz[2], Fwx[2], Fwy[2], Fwz[2];
    double Kx[2], Ky[2], Kz[2], N2x[2], N2y[2], N2z[2];
    double qnx[2], qny[2], qnz[2];

    #pragma unroll
    for (int k = 0; k < 2; ++k) {
        int p = 2*t + k;
        vld[k] = valid_ws[p];
        int f = fidx_ws[p];
        int i0 = mF[3*f+0], i1 = mF[3*f+1], i2 = mF[3*f+2];
        double V0x = mV[3*i0+0], V0y = mV[3*i0+1], V0z = mV[3*i0+2];
        double V1x = mV[3*i1+0], V1y = mV[3*i1+1], V1z = mV[3*i1+2];
        double V2x = mV[3*i2+0], V2y = mV[3*i2+1], V2z = mV[3*i2+2];
        double n0x = mN[3*i0+0], n0y = mN[3*i0+1], n0z = mN[3*i0+2];
        double n1x = mN[3*i1+0], n1y = mN[3*i1+1], n1z = mN[3*i1+2];
        N2x[k] = mN[3*i2+0]; N2y[k] = mN[3*i2+1]; N2z[k] = mN[3*i2+2];
        double qx = qV[3*p+0], qy = qV[3*p+1], qz = qV[3*p+2];
        qnx[k] = qN[3*p+0]; qny[k] = qN[3*p+1]; qnz[k] = qN[3*p+2];
        Eux[k] = V0x - V2x; Euy[k] = V0y - V2y; Euz[k] = V0z - V2z;
        Ewx[k] = V1x - V2x; Ewy[k] = V1y - V2y; Ewz[k] = V1z - V2z;
        Fux[k] = n0x - N2x[k]; Fuy[k] = n0y - N2y[k]; Fuz[k] = n0z - N2z[k];
        Fwx[k] = n1x - N2x[k]; Fwy[k] = n1y - N2y[k]; Fwz[k] = n1z - N2z[k];
        Kx[k] = V2x - qx; Ky[k] = V2y - qy; Kz[k] = V2z - qz;
    }

    double u[2], w[2];
    #pragma unroll
    for (int k = 0; k < 2; ++k) { u[k] = 1.0/3.0; w[k] = 1.0/3.0; }
    double alpha = 1.0;
    for (int outer = 0; outer < 2; ++outer) {
        double du[2] = {0.0, 0.0}, dw[2] = {0.0, 0.0};
        double su[2] = {0.0, 0.0}, sw[2] = {0.0, 0.0};
        for (int it = 0; it < 50; ++it) {
            double clr = clrtab[it];
            #pragma unroll
            for (int k = 0; k < 2; ++k) {
                double uu = u[k] + du[k], ww = w[k] + dw[k];
                // position term: rv = uu*Eu + ww*Ew + K
                double rvx = uu*Eux[k] + ww*Ewx[k] + Kx[k];
                double rvy = uu*Euy[k] + ww*Ewy[k] + Ky[k];
                double rvz = uu*Euz[k] + ww*Ewz[k] + Kz[k];
                double L2v = rvx*rvx + rvy*rvy + rvz*rvz;
                double invLv = rsqrt(L2v);
                double gu = (rvx*Eux[k] + rvy*Euy[k] + rvz*Euz[k]) * invLv;
                double gw = (rvx*Ewx[k] + rvy*Ewy[k] + rvz*Ewz[k]) * invLv;
                // normal term: n = uu*Fu + ww*Fw + N2
                double nx = uu*Fux[k] + ww*Fwx[k] + N2x[k];
                double ny = uu*Fuy[k] + ww*Fwy[k] + N2y[k];
                double nz = uu*Fuz[k] + ww*Fwz[k] + N2z[k];
                double m2 = nx*nx + ny*ny + nz*nz;
                bool   mok = (m2 > 1e-24);           // <=> m > 1e-12
                double inv = mok ? rsqrt(m2) : 1e12; // 1/max(m,1e-12)
                double hx = nx*inv, hy = ny*inv, hz = nz*inv;
                double rnx = hx - qnx[k], rny = hy - qny[k], rnz = hz - qnz[k];
                double L2n = rnx*rnx + rny*rny + rnz*rnz;
                double invLn = rsqrt(L2n);
                double A_u = rnx*Fux[k] + rny*Fuy[k] + rnz*Fuz[k];
                double A_w = rnx*Fwx[k] + rny*Fwy[k] + rnz*Fwz[k];
                double B   = rnx*nx + rny*ny + rnz*nz;
                double C_u = nx*Fux[k] + ny*Fuy[k] + nz*Fuz[k];
                double C_w = nx*Fwx[k] + ny*Fwy[k] + nz*Fwz[k];
                double s = mok ? ((B*inv)*inv)*inv : 0.0;
                double gnu = (A_u*inv - s*C_u) * invLn;
                double gnw = (A_w*inv - s*C_w) * invLn;
                gu = (gu + 0.01*gnu) * inv_denom;
                gw = (gw + 0.01*gnw) * inv_denom;
                su[k] += gu*gu; sw[k] += gw*gw;
                du[k] -= clr * gu / (sqrt(su[k]) + 1e-10);
                dw[k] -= clr * gw / (sqrt(sw[k]) + 1e-10);
            }
        }
        #pragma unroll
        for (int k = 0; k < 2; ++k) { u[k] += du[k] * alpha; w[k] += dw[k] * alpha; }
        alpha *= 0.5;
    }
    #pragma unroll
    for (int k = 0; k < 2; ++k) {
        int p = 2*t + k;
        out[NP + 2*p + 0] = vld[k] ? (float)u[k] : third;
        out[NP + 2*p + 1] = vld[k] ? (float)w[k] : third;
    }
}

// ---------------------------------------------------------------------------
extern "C" void kernel_launch(void* const* d_in, const int* in_sizes, int n_in,
                              void* d_out, int out_size, void* d_ws, size_t ws_size,
                              hipStream_t stream) {
    const float* qV = (const float*)d_in[0];   // query_V [1,8192,3]
    const float* qN = (const float*)d_in[1];   // query_N [1,8192,3]
    const float* mV = (const float*)d_in[2];   // mesh_V  [16384,3]
    const int*   mF = (const int*)d_in[3];     // mesh_F  [16384,3] int32
    const float* mN = (const float*)d_in[4];   // mesh_N  [16384,3]
    float* out = (float*)d_out;                // fidx | vw | outlier_mask

    double* ctr      = (double*)d_ws;          // NF*4 doubles (cx,cy,cz,|c|^2)
    double* denom    = ctr + (size_t)NF*4;     // 1 double
    double* clrtab   = denom + 1;              // 50 doubles
    int*    fidx_ws  = (int*)(clrtab + 50);    // NP ints
    int*    valid_ws = fidx_ws + NP;           // NP ints

    hipLaunchKernelGGL(k_centers, dim3(NF/256),    dim3(256), 0, stream, mV, mF, ctr, clrtab);
    hipLaunchKernelGGL(k_knn,     dim3(NP/GQ),     dim3(256), 0, stream, qV, ctr, out, fidx_ws, valid_ws);
    hipLaunchKernelGGL(k_denom,   dim3(1),         dim3(256), 0, stream, valid_ws, denom);
    hipLaunchKernelGGL(k_opt,     dim3(NP/2/64),   dim3(64),  0, stream,
                       qV, qN, mV, mF, mN, fidx_ws, valid_ws, denom, clrtab, out);
}